// Round 1
// baseline (89.244 us; speedup 1.0000x reference)
//
#include <hip/hip_runtime.h>

#define NT     10
#define NBATCH 16
#define SEQ    512
#define NSTATE 100   // NT*NT (a=source type, m=target type)
#define KSTEPS 10

__global__ __launch_bounds__(128) void hawkes_scan(
    const float* __restrict__ times,   // [B,S]
    const int*   __restrict__ types,   // [B,S]
    const float* __restrict__ Tptr,    // [1]
    const float* __restrict__ mu,      // [NT]
    const float* __restrict__ alpha,   // [NT,NT]
    const float* __restrict__ beta,    // [NT,NT]
    float*       __restrict__ partial) // [B][2] = {integral_part, loglik}
{
    __shared__ float s_t[SEQ];
    __shared__ int   s_ty[SEQ];
    __shared__ float s_red[4];

    const int b = blockIdx.x;
    const int t = threadIdx.x;

    const float* bt  = times + b * SEQ;
    const int*   bty = types + b * SEQ;
    for (int i = t; i < SEQ; i += 128) { s_t[i] = bt[i]; s_ty[i] = bty[i]; }
    __syncthreads();

    const bool active = (t < NSTATE);
    const int a = t / NT;        // source (exciting) event type
    const int m = t - a * NT;    // target type / column
    float al = 0.f, be = 0.f, mum = 0.f;
    if (active) {
        al  = alpha[a * NT + m];
        be  = beta[a * NT + m];
        mum = (a == 0) ? mu[m] : 0.f;   // lane (0,m) owns the mu[ty] term
    }
    const float T = Tptr[0];

    float g      = 0.f;   // sum_{j<k, ty_j==a} exp(-be*(s_k - t_j))
    float integ  = 0.f;   // sum_k al*g*geom*h
    float loglik = 0.f;   // sum_i [mu[ty_i]] + al*g'  (for m == ty_i)

    float s = 0.f;
    #pragma unroll 4
    for (int k = 0; k <= SEQ; ++k) {
        const float e = (k == SEQ) ? T : s_t[k];
        const float h = (e - s) * (1.0f / KSTEPS);
        s = e;
        const float x   = be * h;
        const float e1  = __expf(-x);
        const float e10 = __expf(-10.f * x);
        // geom = sum_{p=0}^{10} e^{-p x}
        float geom;
        if (x > 1e-3f) geom = (1.f - e10 * e1) / (1.f - e1);
        else           geom = 11.f + x * (-55.f + 192.5f * x);
        integ = fmaf(al * g * geom, h, integ);
        g *= e10;            // state now at time e (= t_k for k<SEQ)
        if (k < SEQ) {
            const int ty = s_ty[k];
            if (active && ty == m) loglik += fmaf(al, g, mum); // strict j<k: before +1
            if (active && ty == a) g += 1.f;
        }
    }

    // block reduction of (integ, loglik)
    float v0 = integ, v1 = loglik;
    for (int off = 32; off > 0; off >>= 1) {
        v0 += __shfl_down(v0, off);
        v1 += __shfl_down(v1, off);
    }
    const int wave = t >> 6, lane = t & 63;
    if (lane == 0) { s_red[wave * 2 + 0] = v0; s_red[wave * 2 + 1] = v1; }
    __syncthreads();
    if (t == 0) {
        partial[b * 2 + 0] = s_red[0] + s_red[2];
        partial[b * 2 + 1] = s_red[1] + s_red[3];
    }
}

__global__ void hawkes_final(const float* __restrict__ partial,
                             const float* __restrict__ mu,
                             const float* __restrict__ Tptr,
                             float* __restrict__ out)
{
    if (threadIdx.x == 0 && blockIdx.x == 0) {
        float I = 0.f, L = 0.f;
        for (int b = 0; b < NBATCH; ++b) {
            I += partial[b * 2 + 0];
            L += partial[b * 2 + 1];
        }
        float mus = 0.f;
        for (int i = 0; i < NT; ++i) mus += mu[i];
        const float T = Tptr[0];
        // constant quadrature term: B * (STEPS+1) * sum(mu) * (sum_k h_k = T/STEPS)
        I += (float)NBATCH * (float)(KSTEPS + 1) * mus * T * (1.0f / KSTEPS);
        out[0] = I - L;   // -(loglik - integral)
    }
}

extern "C" void kernel_launch(void* const* d_in, const int* in_sizes, int n_in,
                              void* d_out, int out_size, void* d_ws, size_t ws_size,
                              hipStream_t stream) {
    const float* times = (const float*)d_in[0];
    const int*   types = (const int*)d_in[1];
    const float* T     = (const float*)d_in[2];
    const float* mu    = (const float*)d_in[3];
    const float* alpha = (const float*)d_in[4];
    const float* beta  = (const float*)d_in[5];
    float* partials = (float*)d_ws;   // 16*2 floats = 128 B

    hawkes_scan<<<NBATCH, 128, 0, stream>>>(times, types, T, mu, alpha, beta, partials);
    hawkes_final<<<1, 64, 0, stream>>>(partials, mu, T, (float*)d_out);
}

// Round 2
// 18.762 us; speedup vs baseline: 4.7567x; 4.7567x over previous
//
#include <hip/hip_runtime.h>

#define NT     10
#define NBATCH 16
#define SEQ    512
#define KSTEPS 10

// Per chunk, per state (a,m): affine coefficients over the chunk's intervals
//   g_out    = A*g_in + B      (B = local g built inside chunk)
//   integral = C*g_in + D
//   loglik   = E*g_in + F
// part layout: [b*NC + c][6][128]  (lane = state index, coalesced)

template<int NC>
__global__ __launch_bounds__(128) void hawkes_chunk(
    const float* __restrict__ times,   // [B,S]
    const int*   __restrict__ types,   // [B,S]
    const float* __restrict__ Tptr,
    const float* __restrict__ mu,
    const float* __restrict__ alpha,
    const float* __restrict__ beta,
    float*       __restrict__ part)
{
    constexpr int L = SEQ / NC;
    __shared__ float s_t[L + 1];   // s_t[i] = t[k0-1+i]  (t[-1] := 0)
    __shared__ int   s_ty[L];

    const int blk = blockIdx.x;
    const int b   = blk / NC;
    const int c   = blk % NC;
    const int t   = threadIdx.x;
    const int k0  = c * L;

    const float* bt  = times + b * SEQ;
    const int*   bty = types + b * SEQ;
    for (int i = t; i <= L; i += 128) {
        const int j = k0 - 1 + i;
        s_t[i] = (j >= 0) ? bt[j] : 0.f;
    }
    for (int i = t; i < L; i += 128) s_ty[i] = bty[k0 + i];
    __syncthreads();

    const bool active = (t < NT * NT);
    const int a = t / NT;
    const int m = t - a * NT;
    float al = 0.f, be = 0.f, mum = 0.f;
    if (active) {
        al  = alpha[a * NT + m];
        be  = beta [a * NT + m];
        mum = (a == 0) ? mu[m] : 0.f;
    }

    float A = 1.f, gl = 0.f, C = 0.f, D = 0.f, E = 0.f, F = 0.f;
    float tprev = s_t[0];

    #pragma unroll 8
    for (int i = 0; i < L; ++i) {
        const float te  = s_t[i + 1];
        const float h   = (te - tprev) * (1.0f / KSTEPS);
        tprev = te;
        const float x    = be * h;
        const float e1   = __expf(-x);
        const float e10  = __expf(-10.f * x);
        const float gA   = (1.f - e10 * e1) * __builtin_amdgcn_rcpf(1.f - e1);
        const float gB   = 11.f + x * (-55.f + 192.5f * x);
        const float geom = (x > 1e-3f) ? gA : gB;
        const float coef = al * geom * h;
        C = fmaf(coef, A,  C);
        D = fmaf(coef, gl, D);
        A  *= e10;
        gl *= e10;
        const int ty = s_ty[i];
        E  = (ty == m) ? fmaf(al, A,  E) : E;            // after decay, before +1
        F  = (ty == m) ? (F + fmaf(al, gl, mum)) : F;
        gl += (ty == a) ? 1.f : 0.f;
    }
    if (c == NC - 1) {   // final interval (t_{S-1}, T], quadrature only
        const float h    = (Tptr[0] - tprev) * (1.0f / KSTEPS);
        const float x    = be * h;
        const float e1   = __expf(-x);
        const float e10  = __expf(-10.f * x);
        const float gA   = (1.f - e10 * e1) * __builtin_amdgcn_rcpf(1.f - e1);
        const float gB   = 11.f + x * (-55.f + 192.5f * x);
        const float geom = (x > 1e-3f) ? gA : gB;
        const float coef = al * geom * h;
        C = fmaf(coef, A,  C);
        D = fmaf(coef, gl, D);
    }

    float* p = part + (size_t)blk * 6 * 128 + t;
    p[0]   = A;  p[128] = gl;
    p[256] = C;  p[384] = D;
    p[512] = E;  p[640] = F;
}

template<int NC>
__global__ __launch_bounds__(1024) void hawkes_combine(
    const float* __restrict__ part,
    const float* __restrict__ mu,
    const float* __restrict__ Tptr,
    float*       __restrict__ out)
{
    const int tid = threadIdx.x;
    float I = 0.f, Lk = 0.f;
    #pragma unroll
    for (int pass = 0; pass < 2; ++pass) {
        const int b    = pass * 8 + (tid >> 7);
        const int lane = tid & 127;
        float g = 0.f;
        #pragma unroll
        for (int c = 0; c < NC; ++c) {
            const float* p = part + (size_t)(b * NC + c) * 768 + lane;
            const float A  = p[0],   B_ = p[128];
            const float C  = p[256], D  = p[384];
            const float E  = p[512], F  = p[640];
            I  += fmaf(C, g, D);
            Lk += fmaf(E, g, F);
            g   = fmaf(A, g, B_);
        }
    }
    float v0 = I, v1 = Lk;
    for (int off = 32; off; off >>= 1) {
        v0 += __shfl_down(v0, off);
        v1 += __shfl_down(v1, off);
    }
    __shared__ float red[32];
    const int w = tid >> 6, ln = tid & 63;
    if (ln == 0) { red[w * 2] = v0; red[w * 2 + 1] = v1; }
    __syncthreads();
    if (tid == 0) {
        float It = 0.f, Lt = 0.f;
        #pragma unroll
        for (int i = 0; i < 16; ++i) { It += red[i * 2]; Lt += red[i * 2 + 1]; }
        float mus = 0.f;
        #pragma unroll
        for (int i = 0; i < NT; ++i) mus += mu[i];
        // constant quadrature term: B * (STEPS+1) * sum(mu) * (T/STEPS)
        It += (float)NBATCH * (float)(KSTEPS + 1) * mus * Tptr[0] * (1.0f / KSTEPS);
        out[0] = It - Lt;
    }
}

extern "C" void kernel_launch(void* const* d_in, const int* in_sizes, int n_in,
                              void* d_out, int out_size, void* d_ws, size_t ws_size,
                              hipStream_t stream) {
    const float* times = (const float*)d_in[0];
    const int*   types = (const int*)d_in[1];
    const float* T     = (const float*)d_in[2];
    const float* mu    = (const float*)d_in[3];
    const float* alpha = (const float*)d_in[4];
    const float* beta  = (const float*)d_in[5];
    float* part = (float*)d_ws;
    float* out  = (float*)d_out;

    const size_t per = (size_t)NBATCH * 6 * 128 * sizeof(float);  // 48 KiB per chunk-slot

    if (ws_size >= 16 * per) {
        hawkes_chunk<16><<<NBATCH * 16, 128, 0, stream>>>(times, types, T, mu, alpha, beta, part);
        hawkes_combine<16><<<1, 1024, 0, stream>>>(part, mu, T, out);
    } else if (ws_size >= 8 * per) {
        hawkes_chunk<8><<<NBATCH * 8, 128, 0, stream>>>(times, types, T, mu, alpha, beta, part);
        hawkes_combine<8><<<1, 1024, 0, stream>>>(part, mu, T, out);
    } else if (ws_size >= 4 * per) {
        hawkes_chunk<4><<<NBATCH * 4, 128, 0, stream>>>(times, types, T, mu, alpha, beta, part);
        hawkes_combine<4><<<1, 1024, 0, stream>>>(part, mu, T, out);
    } else if (ws_size >= 2 * per) {
        hawkes_chunk<2><<<NBATCH * 2, 128, 0, stream>>>(times, types, T, mu, alpha, beta, part);
        hawkes_combine<2><<<1, 1024, 0, stream>>>(part, mu, T, out);
    } else {
        hawkes_chunk<1><<<NBATCH * 1, 128, 0, stream>>>(times, types, T, mu, alpha, beta, part);
        hawkes_combine<1><<<1, 1024, 0, stream>>>(part, mu, T, out);
    }
}